// Round 8
// baseline (474.194 us; speedup 1.0000x reference)
//
#include <hip/hip_runtime.h>

typedef float f32x4 __attribute__((ext_vector_type(4)));
typedef short bf16x8 __attribute__((ext_vector_type(8)));

__device__ __forceinline__ unsigned short f2bf(float f) {
  unsigned int u = __float_as_uint(f);
  u += 0x7FFFu + ((u >> 16) & 1u);  // RNE
  return (unsigned short)(u >> 16);
}

// ---------------- build node -> compact id map ----------------
__global__ void k_build_map(const int* __restrict__ tri_nodes, int* __restrict__ map,
                            int* __restrict__ uniq, int* __restrict__ counter, int n) {
  int i = blockIdx.x * blockDim.x + threadIdx.x;
  if (i >= n) return;
  int node = tri_nodes[i];
  int old = atomicCAS(&map[node], -1, -2);
  if (old == -1) {
    int mid = atomicAdd(counter, 1);
    uniq[mid] = node;
    map[node] = mid;
  }
}

// ---------------- count needed edges per comb = rel*nt + mid ----------------
__global__ void k_count(const int* __restrict__ edst, const int* __restrict__ erel,
                        const int* __restrict__ map, int* __restrict__ cnt_c,
                        int nt, int E) {
  int stride = gridDim.x * blockDim.x;
  for (int i = blockIdx.x * blockDim.x + threadIdx.x; i < E; i += stride) {
    int mid = map[edst[i]];
    if (mid >= 0) atomicAdd(&cnt_c[erel[i] * nt + mid], 1);
  }
}

// ---------------- hierarchical exclusive scan over M=262144 entries ----------------
__global__ __launch_bounds__(256) void k_scan_s1(const int* __restrict__ cnt_c,
                                                 int* __restrict__ bsum) {
  __shared__ int sh[256];
  int tid = threadIdx.x;
  int base = blockIdx.x * 1024 + tid * 4;
  int s = cnt_c[base] + cnt_c[base + 1] + cnt_c[base + 2] + cnt_c[base + 3];
  sh[tid] = s;
  __syncthreads();
  for (int o = 1; o < 256; o <<= 1) {
    int x = (tid >= o) ? sh[tid - o] : 0;
    __syncthreads();
    sh[tid] += x;
    __syncthreads();
  }
  if (tid == 255) bsum[blockIdx.x] = sh[255];
}
__global__ __launch_bounds__(256) void k_scan_s2(int* __restrict__ bsum,
                                                 int* __restrict__ seg_start, int M) {
  __shared__ int sh[256];
  int tid = threadIdx.x;
  int v = bsum[tid];
  sh[tid] = v;
  __syncthreads();
  for (int o = 1; o < 256; o <<= 1) {
    int x = (tid >= o) ? sh[tid - o] : 0;
    __syncthreads();
    sh[tid] += x;
    __syncthreads();
  }
  bsum[tid] = sh[tid] - v;  // exclusive
  if (tid == 255) seg_start[M] = sh[255];
}
__global__ __launch_bounds__(256) void k_scan_s3(const int* __restrict__ cnt_c,
                                                 const int* __restrict__ bsum,
                                                 int* __restrict__ seg_start,
                                                 int* __restrict__ seg_ofs) {
  __shared__ int sh[256];
  int tid = threadIdx.x;
  int base = blockIdx.x * 1024 + tid * 4;
  int c0 = cnt_c[base], c1 = cnt_c[base + 1], c2 = cnt_c[base + 2], c3 = cnt_c[base + 3];
  int s = c0 + c1 + c2 + c3;
  sh[tid] = s;
  __syncthreads();
  for (int o = 1; o < 256; o <<= 1) {
    int x = (tid >= o) ? sh[tid - o] : 0;
    __syncthreads();
    sh[tid] += x;
    __syncthreads();
  }
  int run = bsum[blockIdx.x] + sh[tid] - s;
  seg_start[base] = run; seg_ofs[base] = run; run += c0;
  seg_start[base + 1] = run; seg_ofs[base + 1] = run; run += c1;
  seg_start[base + 2] = run; seg_ofs[base + 2] = run; run += c2;
  seg_start[base + 3] = run; seg_ofs[base + 3] = run;
}

// ---------------- scatter packed (mid<<17|src) into (rel,mid)-sorted order ----------------
__global__ void k_scatter(const int* __restrict__ esrc, const int* __restrict__ edst,
                          const int* __restrict__ erel, const int* __restrict__ map,
                          int* __restrict__ seg_ofs, int* __restrict__ s_pk,
                          int nt, int E) {
  int stride = gridDim.x * blockDim.x;
  for (int i = blockIdx.x * blockDim.x + threadIdx.x; i < E; i += stride) {
    int mid = map[edst[i]];
    if (mid >= 0) {
      int comb = erel[i] * nt + mid;
      int pos = atomicAdd(&seg_ofs[comb], 1);
      s_pk[pos] = (mid << 17) | esrc[i];
    }
  }
}

// ---------------- W -> bf16 transposed [r][col=e][k=d] (aliases dead cnt_c) ----------------
__global__ void k_cvt_w(const float* __restrict__ W_rel, const float* __restrict__ W_self,
                        unsigned short* __restrict__ Wt) {
  int i = blockIdx.x * 256 + threadIdx.x;  // over 9*16384
  if (i >= 9 * 16384) return;
  int r = i >> 14, rem = i & 16383;
  int e = rem >> 7, d = rem & 127;
  float v = (r < 8) ? W_rel[r * 16384 + d * 128 + e] : W_self[d * 128 + e];
  Wt[i] = f2bf(v);
}

// ---------------- fused RGCN GEMM on matrix cores, edge-parallel gather ----------------
// 64-mid tile, 512 threads (8 waves, 2x4 wave grid, 32x32 sub-tile/wave).
// Phase r<8: zero fp32 LDS accum -> flat edge loop (8 thr/edge, ds_add_f32)
// -> scale+cvt -> swizzled bf16 a_lds -> MFMA. B-fragments are loaded straight
// from L2-resident Wt into registers (no w_lds). Phase 8: self rows + W_self.
__global__ __launch_bounds__(512) void k_fused(
    const float* __restrict__ X, const unsigned short* __restrict__ Wt,
    const float* __restrict__ bvec, const int* __restrict__ uniq,
    const int* __restrict__ counter, const int* __restrict__ seg_start,
    const int* __restrict__ s_pk, float* __restrict__ Hacc) {
  __shared__ float a_acc[64 * 132];                         // 33.8 KB fp32 accum (pad 132)
  __shared__ __align__(16) unsigned short a_lds[64 * 128];  // 16 KB bf16, 16B-unit swizzled

  int nm = *counter;
  int mid0 = blockIdx.x * 64;
  if (mid0 >= nm) return;

  int t = threadIdx.x;
  int er = t >> 3, oct = t & 7;                   // staging: row er, 16-elem chunk oct
  int lane = t & 63, l15 = lane & 15, lg = lane >> 4;
  int wid = t >> 6, wr = wid >> 2, wc = wid & 3;  // wave sub-tile (32 rows x 32 cols)

  f32x4 acc[2][2];
#pragma unroll
  for (int m = 0; m < 2; ++m)
#pragma unroll
    for (int n = 0; n < 2; ++n) {
      f32x4 z = {0.f, 0.f, 0.f, 0.f};
      acc[m][n] = z;
    }

  for (int r = 0; r < 9; ++r) {
    __syncthreads();  // top: prev MFMA done with a_lds, prev convert done with a_acc

    // B fragments direct from global (Wt is L2-hot: 288 KB read by all blocks)
    bf16x8 bfr[2][4];
    {
      const unsigned short* wb = Wt + r * 16384;
#pragma unroll
      for (int n = 0; n < 2; ++n)
#pragma unroll
        for (int kb = 0; kb < 4; ++kb)
          bfr[n][kb] = *(const bf16x8*)(wb + (wc * 32 + n * 16 + l15) * 128 + (kb * 4 + lg) * 8);
    }

    float aa[16];
    if (r < 8) {
      for (int i = t; i < 64 * 132; i += 512) a_acc[i] = 0.f;
      __syncthreads();  // zero visible before atomics

      int base = r * 32768 + mid0;
      int e0 = seg_start[base], e1 = seg_start[base + 64];
      for (int p = t >> 3; e0 + p < e1; p += 64) {  // 8 threads per edge, 64 edges/pass
        unsigned pk = (unsigned)s_pk[e0 + p];
        int src = pk & 0x1FFFF;
        int row = (int)(pk >> 17) - mid0;
        const float4* xr = (const float4*)(X + (size_t)src * 128) + oct * 4;
        float* dst = a_acc + row * 132 + oct * 16;
#pragma unroll
        for (int q = 0; q < 4; ++q) {
          float4 v = xr[q];
          atomicAdd(dst + q * 4 + 0, v.x);
          atomicAdd(dst + q * 4 + 1, v.y);
          atomicAdd(dst + q * 4 + 2, v.z);
          atomicAdd(dst + q * 4 + 3, v.w);
        }
      }
      __syncthreads();  // gather done

      int cnt = seg_start[base + er + 1] - seg_start[base + er];
      float sc = (cnt > 1) ? (1.0f / (float)cnt) : 1.0f;
#pragma unroll
      for (int j = 0; j < 16; ++j) aa[j] = a_acc[er * 132 + oct * 16 + j] * sc;
    } else {
#pragma unroll
      for (int j = 0; j < 16; ++j) aa[j] = 0.f;
      int mid = mid0 + er;
      if (mid < nm) {
        const float4* xr = (const float4*)(X + (size_t)uniq[mid] * 128) + oct * 4;
#pragma unroll
        for (int q = 0; q < 4; ++q) {
          float4 v = xr[q];
          aa[q * 4 + 0] = v.x; aa[q * 4 + 1] = v.y;
          aa[q * 4 + 2] = v.z; aa[q * 4 + 3] = v.w;
        }
      }
    }

    {  // pack bf16 + swizzled store to a_lds
      unsigned int p[8];
#pragma unroll
      for (int q = 0; q < 8; ++q)
        p[q] = (unsigned int)f2bf(aa[q * 2]) | ((unsigned int)f2bf(aa[q * 2 + 1]) << 16);
      int unit0 = er * 16 + oct * 2, sw = er & 7;
      uint4 p0 = make_uint4(p[0], p[1], p[2], p[3]);
      uint4 p1 = make_uint4(p[4], p[5], p[6], p[7]);
      *(uint4*)&a_lds[((unit0) ^ sw) * 8] = p0;
      *(uint4*)&a_lds[((unit0 + 1) ^ sw) * 8] = p1;
    }
    __syncthreads();  // a_lds ready

    // ---- MFMA: 4 k-blocks x (2 row-frags x 2 col-frags), B from registers
#pragma unroll
    for (int kb = 0; kb < 4; ++kb) {
      int ku = kb * 4 + lg;
      bf16x8 af[2];
#pragma unroll
      for (int m = 0; m < 2; ++m) {
        int row = wr * 32 + m * 16 + l15;
        af[m] = *(const bf16x8*)&a_lds[((row * 16 + ku) ^ (row & 7)) * 8];
      }
#pragma unroll
      for (int m = 0; m < 2; ++m)
#pragma unroll
        for (int n = 0; n < 2; ++n)
          acc[m][n] = __builtin_amdgcn_mfma_f32_16x16x32_bf16(af[m], bfr[n][kb], acc[m][n], 0, 0, 0);
    }
  }

  // epilogue: bias + relu, plain stores. C/D map: col=lane&15, row=(lane>>4)*4+reg
#pragma unroll
  for (int m = 0; m < 2; ++m) {
#pragma unroll
    for (int n = 0; n < 2; ++n) {
      int col = wc * 32 + n * 16 + l15;
      float bv = bvec[col];
#pragma unroll
      for (int q = 0; q < 4; ++q) {
        int row = mid0 + wr * 32 + m * 16 + lg * 4 + q;
        float v = acc[m][n][q] + bv;
        Hacc[(size_t)row * 128 + col] = v > 0.f ? v : 0.f;
      }
    }
  }
}

// ---------------- DistMult score: one wave per triple ----------------
__global__ void k_score(const float* __restrict__ H, const int* __restrict__ map,
                        const float* __restrict__ rel_emb, const int* __restrict__ tri_nodes,
                        const int* __restrict__ tri_rel, float* __restrict__ out, int B) {
  int w = (blockIdx.x * blockDim.x + threadIdx.x) >> 6;
  int lane = threadIdx.x & 63;
  if (w >= B) return;
  int s = map[tri_nodes[w * 2]];
  int o = map[tri_nodes[w * 2 + 1]];
  const float* hs = H + (size_t)s * 128;
  const float* ho = H + (size_t)o * 128;
  const float* rr = rel_emb + (size_t)tri_rel[w] * 128;
  float p = hs[lane] * ho[lane] * rr[lane] + hs[lane + 64] * ho[lane + 64] * rr[lane + 64];
#pragma unroll
  for (int ofs = 32; ofs > 0; ofs >>= 1) p += __shfl_down(p, ofs);
  if (lane == 0) out[w] = p;
}

extern "C" void kernel_launch(void* const* d_in, const int* in_sizes, int n_in,
                              void* d_out, int out_size, void* d_ws, size_t ws_size,
                              hipStream_t stream) {
  const float* X       = (const float*)d_in[0];
  const float* W_rel   = (const float*)d_in[1];
  const float* W_self  = (const float*)d_in[2];
  const float* bvec    = (const float*)d_in[3];
  const float* rel_emb = (const float*)d_in[4];
  const int* edge_src  = (const int*)d_in[5];
  const int* edge_dst  = (const int*)d_in[6];
  const int* edge_rel  = (const int*)d_in[7];
  const int* tri_nodes = (const int*)d_in[8];
  const int* tri_rel   = (const int*)d_in[9];

  int N  = in_sizes[0] / 128;   // 100000
  int E  = in_sizes[5];         // 1600000
  int nt = in_sizes[8];         // 2*B = 32768
  int B  = in_sizes[9];         // 16384
  int M  = nt * 8;              // 262144 combs

  char* ws = (char*)d_ws;
  int* map       = (int*)ws;                 // N
  int* counter   = map + N;                  // 1 (+pad 64)
  int* uniq      = counter + 64;             // nt
  int* cnt_c     = uniq + nt;                // M  (reused as Wt after scan_s3)
  int* seg_start = cnt_c + M;                // M+1 (+pad 64)
  int* seg_ofs   = seg_start + M + 64;       // M
  int* bsum      = seg_ofs + M;              // 256
  int* s_pk      = bsum + 256;               // E (packed mid<<17|src)
  float* Hacc    = (float*)(s_pk + E);       // nt*128 floats
  unsigned short* Wt = (unsigned short*)cnt_c;  // 9*16384 bf16, aliases cnt_c
  // total ws use: ~26.9 MB (within the 31.5 MB high-water mark proven in rounds 2-4)

  hipMemsetAsync(map, 0xFF, (size_t)N * 4, stream);  // -1
  hipMemsetAsync(counter, 0, 64 * 4, stream);
  hipMemsetAsync(cnt_c, 0, (size_t)M * 4, stream);

  k_build_map<<<(nt + 255) / 256, 256, 0, stream>>>(tri_nodes, map, uniq, counter, nt);
  k_count<<<1024, 256, 0, stream>>>(edge_dst, edge_rel, map, cnt_c, nt, E);
  k_scan_s1<<<256, 256, 0, stream>>>(cnt_c, bsum);
  k_scan_s2<<<1, 256, 0, stream>>>(bsum, seg_start, M);
  k_scan_s3<<<256, 256, 0, stream>>>(cnt_c, bsum, seg_start, seg_ofs);
  // cnt_c is dead from here on; overwrite it with the bf16 weights
  k_cvt_w<<<(9 * 16384 + 255) / 256, 256, 0, stream>>>(W_rel, W_self, Wt);
  k_scatter<<<1024, 256, 0, stream>>>(edge_src, edge_dst, edge_rel, map, seg_ofs,
                                      s_pk, nt, E);
  k_fused<<<nt / 64, 512, 0, stream>>>(X, Wt, bvec, uniq, counter, seg_start, s_pk, Hacc);
  k_score<<<(B * 64 + 255) / 256, 256, 0, stream>>>(Hacc, map, rel_emb, tri_nodes,
                                                    tri_rel, (float*)d_out, B);
}

// Round 9
// 178.758 us; speedup vs baseline: 2.6527x; 2.6527x over previous
//
#include <hip/hip_runtime.h>

typedef float f32x4 __attribute__((ext_vector_type(4)));
typedef short bf16x8 __attribute__((ext_vector_type(8)));

__device__ __forceinline__ unsigned short f2bf(float f) {
  unsigned int u = __float_as_uint(f);
  u += 0x7FFFu + ((u >> 16) & 1u);  // RNE
  return (unsigned short)(u >> 16);
}

// ---------------- build node -> compact id map ----------------
__global__ void k_build_map(const int* __restrict__ tri_nodes, int* __restrict__ map,
                            int* __restrict__ uniq, int* __restrict__ counter, int n) {
  int i = blockIdx.x * blockDim.x + threadIdx.x;
  if (i >= n) return;
  int node = tri_nodes[i];
  int old = atomicCAS(&map[node], -1, -2);
  if (old == -1) {
    int mid = atomicAdd(counter, 1);
    uniq[mid] = node;
    map[node] = mid;
  }
}

// ---------------- count needed edges per comb = mid*8+rel ----------------
__global__ void k_count(const int* __restrict__ edst, const int* __restrict__ erel,
                        const int* __restrict__ map, int* __restrict__ cnt_c, int E) {
  int stride = gridDim.x * blockDim.x;
  for (int i = blockIdx.x * blockDim.x + threadIdx.x; i < E; i += stride) {
    int mid = map[edst[i]];
    if (mid >= 0) atomicAdd(&cnt_c[mid * 8 + erel[i]], 1);
  }
}

// ---------------- hierarchical exclusive scan over M=262144 entries ----------------
__global__ __launch_bounds__(256) void k_scan_s1(const int* __restrict__ cnt_c,
                                                 int* __restrict__ bsum) {
  __shared__ int sh[256];
  int tid = threadIdx.x;
  int base = blockIdx.x * 1024 + tid * 4;
  int s = cnt_c[base] + cnt_c[base + 1] + cnt_c[base + 2] + cnt_c[base + 3];
  sh[tid] = s;
  __syncthreads();
  for (int o = 1; o < 256; o <<= 1) {
    int x = (tid >= o) ? sh[tid - o] : 0;
    __syncthreads();
    sh[tid] += x;
    __syncthreads();
  }
  if (tid == 255) bsum[blockIdx.x] = sh[255];
}
__global__ __launch_bounds__(256) void k_scan_s2(int* __restrict__ bsum,
                                                 int* __restrict__ seg_start, int M) {
  __shared__ int sh[256];
  int tid = threadIdx.x;
  int v = bsum[tid];
  sh[tid] = v;
  __syncthreads();
  for (int o = 1; o < 256; o <<= 1) {
    int x = (tid >= o) ? sh[tid - o] : 0;
    __syncthreads();
    sh[tid] += x;
    __syncthreads();
  }
  bsum[tid] = sh[tid] - v;  // exclusive
  if (tid == 255) seg_start[M] = sh[255];
}
__global__ __launch_bounds__(256) void k_scan_s3(const int* __restrict__ cnt_c,
                                                 const int* __restrict__ bsum,
                                                 int* __restrict__ seg_start,
                                                 int* __restrict__ seg_ofs) {
  __shared__ int sh[256];
  int tid = threadIdx.x;
  int base = blockIdx.x * 1024 + tid * 4;
  int c0 = cnt_c[base], c1 = cnt_c[base + 1], c2 = cnt_c[base + 2], c3 = cnt_c[base + 3];
  int s = c0 + c1 + c2 + c3;
  sh[tid] = s;
  __syncthreads();
  for (int o = 1; o < 256; o <<= 1) {
    int x = (tid >= o) ? sh[tid - o] : 0;
    __syncthreads();
    sh[tid] += x;
    __syncthreads();
  }
  int run = bsum[blockIdx.x] + sh[tid] - s;
  seg_start[base] = run; seg_ofs[base] = run; run += c0;
  seg_start[base + 1] = run; seg_ofs[base + 1] = run; run += c1;
  seg_start[base + 2] = run; seg_ofs[base + 2] = run; run += c2;
  seg_start[base + 3] = run; seg_ofs[base + 3] = run;
}

// ---------------- scatter needed edge srcs into comb-sorted order ----------------
__global__ void k_scatter(const int* __restrict__ esrc, const int* __restrict__ edst,
                          const int* __restrict__ erel, const int* __restrict__ map,
                          int* __restrict__ seg_ofs, int* __restrict__ s_src, int E) {
  int stride = gridDim.x * blockDim.x;
  for (int i = blockIdx.x * blockDim.x + threadIdx.x; i < E; i += stride) {
    int mid = map[edst[i]];
    if (mid >= 0) {
      int comb = mid * 8 + erel[i];
      int pos = atomicAdd(&seg_ofs[comb], 1);
      s_src[pos] = esrc[i];
    }
  }
}

// ---------------- W -> bf16 transposed [r][col=e][k=d] (aliases dead cnt_c) ----------------
__global__ void k_cvt_w(const float* __restrict__ W_rel, const float* __restrict__ W_self,
                        unsigned short* __restrict__ Wt) {
  int i = blockIdx.x * 256 + threadIdx.x;  // over 9*16384
  if (i >= 9 * 16384) return;
  int r = i >> 14, rem = i & 16383;
  int e = rem >> 7, d = rem & 127;
  float v = (r < 8) ? W_rel[r * 16384 + d * 128 + e] : W_self[d * 128 + e];
  Wt[i] = f2bf(v);
}

// ---------------- fused RGCN GEMM on matrix cores ----------------
// Round-7 structure (proven 73us) with ONE change: the per-row segment gather
// is branchless register-prefetched (8 idx loads, then 32 independent X loads,
// 0/1-weighted FMA accumulate) instead of a serial dependent loop. Rare
// cnt>8 tail stays serial.
__global__ __launch_bounds__(512) void k_fused(
    const float* __restrict__ X, const unsigned short* __restrict__ Wt,
    const float* __restrict__ bvec, const int* __restrict__ uniq,
    const int* __restrict__ counter, const int* __restrict__ seg_start,
    const int* __restrict__ s_src, float* __restrict__ Hacc) {
  __shared__ __align__(16) unsigned short a_lds[64 * 128];   // [row][k], 16B-unit XOR-swizzled
  __shared__ __align__(16) unsigned short w_lds[128 * 128];  // [col][k], swizzled

  int nm = *counter;
  int mid0 = blockIdx.x * 64;
  if (mid0 >= nm) return;

  int t = threadIdx.x;
  int er = t >> 3, oct = t & 7;                   // staging: row er, 16-elem chunk oct
  int lane = t & 63, l15 = lane & 15, lg = lane >> 4;
  int wid = t >> 6, wr = wid >> 2, wc = wid & 3;  // wave sub-tile (32 rows x 32 cols)
  int mid = mid0 + er;

  f32x4 acc[2][2];
#pragma unroll
  for (int m = 0; m < 2; ++m)
#pragma unroll
    for (int n = 0; n < 2; ++n) {
      f32x4 z = {0.f, 0.f, 0.f, 0.f};
      acc[m][n] = z;
    }

  for (int r = 0; r < 9; ++r) {
    __syncthreads();  // previous compute done before overwriting LDS

    {  // stage W tile: Wt[r] (2048 uint4) -> w_lds, swizzle unit ^ (col&7)
      const uint4* wg = (const uint4*)(Wt + r * 16384);
#pragma unroll
      for (int i = 0; i < 4; ++i) {
        int v = t + i * 512;
        int u = v ^ ((v >> 4) & 7);
        *(uint4*)&w_lds[u * 8] = wg[v];
      }
    }

    {  // stage A row er chunk oct
      float aa[16];
#pragma unroll
      for (int q = 0; q < 16; ++q) aa[q] = 0.f;
      if (r < 8) {
        int comb = mid * 8 + r;
        int s0 = seg_start[comb], s1 = seg_start[comb + 1];
        int cnt = s1 - s0;
        // branchless prefetch of up to 8 edge indices (always in-bounds:
        // s0 <= needed_total < E, s_src has E slots)
        int rowi[8];
        float wj[8];
#pragma unroll
        for (int j = 0; j < 8; ++j) {
          int jj = (j < cnt) ? j : 0;
          int pre = s_src[s0 + jj];
          rowi[j] = (j < cnt) ? pre : 0;    // dummy -> X row 0 (L1-hot)
          wj[j] = (j < cnt) ? 1.f : 0.f;
        }
#pragma unroll
        for (int j = 0; j < 8; ++j) {
          const float4* xr = (const float4*)(X + (size_t)rowi[j] * 128) + oct * 4;
          float w = wj[j];
#pragma unroll
          for (int q = 0; q < 4; ++q) {
            float4 v = xr[q];
            aa[q * 4 + 0] += w * v.x; aa[q * 4 + 1] += w * v.y;
            aa[q * 4 + 2] += w * v.z; aa[q * 4 + 3] += w * v.w;
          }
        }
        for (int e = s0 + 8; e < s1; ++e) {  // rare tail (P[cnt>8] ~ 1e-4)
          const float4* xr = (const float4*)(X + (size_t)s_src[e] * 128) + oct * 4;
#pragma unroll
          for (int q = 0; q < 4; ++q) {
            float4 v = xr[q];
            aa[q * 4 + 0] += v.x; aa[q * 4 + 1] += v.y;
            aa[q * 4 + 2] += v.z; aa[q * 4 + 3] += v.w;
          }
        }
        if (cnt > 1) {
          float sc = 1.0f / (float)cnt;
#pragma unroll
          for (int q = 0; q < 16; ++q) aa[q] *= sc;
        }
      } else if (mid < nm) {
        const float4* xr = (const float4*)(X + (size_t)uniq[mid] * 128) + oct * 4;
#pragma unroll
        for (int q = 0; q < 4; ++q) {
          float4 v = xr[q];
          aa[q * 4 + 0] = v.x; aa[q * 4 + 1] = v.y;
          aa[q * 4 + 2] = v.z; aa[q * 4 + 3] = v.w;
        }
      }
      unsigned int p[8];
#pragma unroll
      for (int q = 0; q < 8; ++q)
        p[q] = (unsigned int)f2bf(aa[q * 2]) | ((unsigned int)f2bf(aa[q * 2 + 1]) << 16);
      int unit0 = er * 16 + oct * 2, sw = er & 7;
      uint4 p0 = make_uint4(p[0], p[1], p[2], p[3]);
      uint4 p1 = make_uint4(p[4], p[5], p[6], p[7]);
      *(uint4*)&a_lds[((unit0) ^ sw) * 8] = p0;
      *(uint4*)&a_lds[((unit0 + 1) ^ sw) * 8] = p1;
    }
    __syncthreads();

    // ---- MFMA: 4 k-blocks x (2 row-frags x 2 col-frags)
#pragma unroll
    for (int kb = 0; kb < 4; ++kb) {
      int ku = kb * 4 + lg;  // 16B unit index along k for this lane group
      bf16x8 af[2], bfr[2];
#pragma unroll
      for (int m = 0; m < 2; ++m) {
        int row = wr * 32 + m * 16 + l15;
        af[m] = *(const bf16x8*)&a_lds[((row * 16 + ku) ^ (row & 7)) * 8];
      }
#pragma unroll
      for (int n = 0; n < 2; ++n) {
        int col = wc * 32 + n * 16 + l15;
        bfr[n] = *(const bf16x8*)&w_lds[((col * 16 + ku) ^ (col & 7)) * 8];
      }
#pragma unroll
      for (int m = 0; m < 2; ++m)
#pragma unroll
        for (int n = 0; n < 2; ++n)
          acc[m][n] = __builtin_amdgcn_mfma_f32_16x16x32_bf16(af[m], bfr[n], acc[m][n], 0, 0, 0);
    }
  }

  // epilogue: bias + relu, plain stores. C/D map: col=lane&15, row=(lane>>4)*4+reg
#pragma unroll
  for (int m = 0; m < 2; ++m) {
#pragma unroll
    for (int n = 0; n < 2; ++n) {
      int col = wc * 32 + n * 16 + l15;
      float bv = bvec[col];
#pragma unroll
      for (int q = 0; q < 4; ++q) {
        int row = mid0 + wr * 32 + m * 16 + lg * 4 + q;
        float v = acc[m][n][q] + bv;
        Hacc[(size_t)row * 128 + col] = v > 0.f ? v : 0.f;
      }
    }
  }
}

// ---------------- DistMult score: one wave per triple ----------------
__global__ void k_score(const float* __restrict__ H, const int* __restrict__ map,
                        const float* __restrict__ rel_emb, const int* __restrict__ tri_nodes,
                        const int* __restrict__ tri_rel, float* __restrict__ out, int B) {
  int w = (blockIdx.x * blockDim.x + threadIdx.x) >> 6;
  int lane = threadIdx.x & 63;
  if (w >= B) return;
  int s = map[tri_nodes[w * 2]];
  int o = map[tri_nodes[w * 2 + 1]];
  const float* hs = H + (size_t)s * 128;
  const float* ho = H + (size_t)o * 128;
  const float* rr = rel_emb + (size_t)tri_rel[w] * 128;
  float p = hs[lane] * ho[lane] * rr[lane] + hs[lane + 64] * ho[lane + 64] * rr[lane + 64];
#pragma unroll
  for (int ofs = 32; ofs > 0; ofs >>= 1) p += __shfl_down(p, ofs);
  if (lane == 0) out[w] = p;
}

extern "C" void kernel_launch(void* const* d_in, const int* in_sizes, int n_in,
                              void* d_out, int out_size, void* d_ws, size_t ws_size,
                              hipStream_t stream) {
  const float* X       = (const float*)d_in[0];
  const float* W_rel   = (const float*)d_in[1];
  const float* W_self  = (const float*)d_in[2];
  const float* bvec    = (const float*)d_in[3];
  const float* rel_emb = (const float*)d_in[4];
  const int* edge_src  = (const int*)d_in[5];
  const int* edge_dst  = (const int*)d_in[6];
  const int* edge_rel  = (const int*)d_in[7];
  const int* tri_nodes = (const int*)d_in[8];
  const int* tri_rel   = (const int*)d_in[9];

  int N  = in_sizes[0] / 128;   // 100000
  int E  = in_sizes[5];         // 1600000
  int nt = in_sizes[8];         // 2*B = 32768
  int B  = in_sizes[9];         // 16384
  int M  = nt * 8;              // 262144 combs

  char* ws = (char*)d_ws;
  int* map       = (int*)ws;                 // N
  int* counter   = map + N;                  // 1 (+pad 64)
  int* uniq      = counter + 64;             // nt
  int* cnt_c     = uniq + nt;                // M  (reused as Wt after scan_s3)
  int* seg_start = cnt_c + M;                // M+1 (+pad 64)
  int* seg_ofs   = seg_start + M + 64;       // M
  int* bsum      = seg_ofs + M;              // 256
  int* s_src     = bsum + 256;               // E
  float* Hacc    = (float*)(s_src + E);      // nt*128 floats
  unsigned short* Wt = (unsigned short*)cnt_c;  // 9*16384 bf16, aliases cnt_c
  // total ws use: ~26.9 MB (within the 31.5 MB high-water mark proven in rounds 2-4)

  hipMemsetAsync(map, 0xFF, (size_t)N * 4, stream);  // -1
  hipMemsetAsync(counter, 0, 64 * 4, stream);
  hipMemsetAsync(cnt_c, 0, (size_t)M * 4, stream);

  int egrid = 4096;  // latency-bound random map probes: spread wider than 1024
  k_build_map<<<(nt + 255) / 256, 256, 0, stream>>>(tri_nodes, map, uniq, counter, nt);
  k_count<<<egrid, 256, 0, stream>>>(edge_dst, edge_rel, map, cnt_c, E);
  k_scan_s1<<<256, 256, 0, stream>>>(cnt_c, bsum);
  k_scan_s2<<<1, 256, 0, stream>>>(bsum, seg_start, M);
  k_scan_s3<<<256, 256, 0, stream>>>(cnt_c, bsum, seg_start, seg_ofs);
  // cnt_c is dead from here on; overwrite it with the bf16 weights
  k_cvt_w<<<(9 * 16384 + 255) / 256, 256, 0, stream>>>(W_rel, W_self, Wt);
  k_scatter<<<egrid, 256, 0, stream>>>(edge_src, edge_dst, edge_rel, map, seg_ofs,
                                       s_src, E);
  k_fused<<<nt / 64, 512, 0, stream>>>(X, Wt, bvec, uniq, counter, seg_start, s_src, Hacc);
  k_score<<<(B * 64 + 255) / 256, 256, 0, stream>>>(Hacc, map, rel_emb, tri_nodes,
                                                    tri_rel, (float*)d_out, B);
}

// Round 10
// 173.025 us; speedup vs baseline: 2.7406x; 1.0331x over previous
//
#include <hip/hip_runtime.h>

typedef float f32x4 __attribute__((ext_vector_type(4)));
typedef short bf16x8 __attribute__((ext_vector_type(8)));

__device__ __forceinline__ unsigned short f2bf(float f) {
  unsigned int u = __float_as_uint(f);
  u += 0x7FFFu + ((u >> 16) & 1u);  // RNE
  return (unsigned short)(u >> 16);
}

// ---------------- build node -> compact id map ----------------
__global__ void k_build_map(const int* __restrict__ tri_nodes, int* __restrict__ map,
                            int* __restrict__ uniq, int* __restrict__ counter, int n) {
  int i = blockIdx.x * blockDim.x + threadIdx.x;
  if (i >= n) return;
  int node = tri_nodes[i];
  int old = atomicCAS(&map[node], -1, -2);
  if (old == -1) {
    int mid = atomicAdd(counter, 1);
    uniq[mid] = node;
    map[node] = mid;
  }
}

// ---------------- count needed edges per comb = mid*8+rel ----------------
__global__ void k_count(const int* __restrict__ edst, const int* __restrict__ erel,
                        const int* __restrict__ map, int* __restrict__ cnt_c, int E) {
  int i = blockIdx.x * blockDim.x + threadIdx.x;
  if (i >= E) return;
  int mid = map[edst[i]];
  if (mid >= 0) atomicAdd(&cnt_c[mid * 8 + erel[i]], 1);
}

// ---------------- hierarchical exclusive scan over M=262144 entries ----------------
__global__ __launch_bounds__(256) void k_scan_s1(const int* __restrict__ cnt_c,
                                                 int* __restrict__ bsum) {
  __shared__ int sh[256];
  int tid = threadIdx.x;
  int base = blockIdx.x * 1024 + tid * 4;
  int s = cnt_c[base] + cnt_c[base + 1] + cnt_c[base + 2] + cnt_c[base + 3];
  sh[tid] = s;
  __syncthreads();
  for (int o = 1; o < 256; o <<= 1) {
    int x = (tid >= o) ? sh[tid - o] : 0;
    __syncthreads();
    sh[tid] += x;
    __syncthreads();
  }
  if (tid == 255) bsum[blockIdx.x] = sh[255];
}
__global__ __launch_bounds__(256) void k_scan_s2(int* __restrict__ bsum,
                                                 int* __restrict__ seg_start, int M) {
  __shared__ int sh[256];
  int tid = threadIdx.x;
  int v = bsum[tid];
  sh[tid] = v;
  __syncthreads();
  for (int o = 1; o < 256; o <<= 1) {
    int x = (tid >= o) ? sh[tid - o] : 0;
    __syncthreads();
    sh[tid] += x;
    __syncthreads();
  }
  bsum[tid] = sh[tid] - v;  // exclusive
  if (tid == 255) seg_start[M] = sh[255];
}
__global__ __launch_bounds__(256) void k_scan_s3(const int* __restrict__ cnt_c,
                                                 const int* __restrict__ bsum,
                                                 int* __restrict__ seg_start,
                                                 int* __restrict__ seg_ofs) {
  __shared__ int sh[256];
  int tid = threadIdx.x;
  int base = blockIdx.x * 1024 + tid * 4;
  int c0 = cnt_c[base], c1 = cnt_c[base + 1], c2 = cnt_c[base + 2], c3 = cnt_c[base + 3];
  int s = c0 + c1 + c2 + c3;
  sh[tid] = s;
  __syncthreads();
  for (int o = 1; o < 256; o <<= 1) {
    int x = (tid >= o) ? sh[tid - o] : 0;
    __syncthreads();
    sh[tid] += x;
    __syncthreads();
  }
  int run = bsum[blockIdx.x] + sh[tid] - s;
  seg_start[base] = run; seg_ofs[base] = run; run += c0;
  seg_start[base + 1] = run; seg_ofs[base + 1] = run; run += c1;
  seg_start[base + 2] = run; seg_ofs[base + 2] = run; run += c2;
  seg_start[base + 3] = run; seg_ofs[base + 3] = run;
}

// ---------------- scatter needed edge srcs into comb-sorted order ----------------
__global__ void k_scatter(const int* __restrict__ esrc, const int* __restrict__ edst,
                          const int* __restrict__ erel, const int* __restrict__ map,
                          int* __restrict__ seg_ofs, int* __restrict__ s_src, int E) {
  int i = blockIdx.x * blockDim.x + threadIdx.x;
  if (i >= E) return;
  int mid = map[edst[i]];
  if (mid >= 0) {
    int comb = mid * 8 + erel[i];
    int pos = atomicAdd(&seg_ofs[comb], 1);
    s_src[pos] = esrc[i];
  }
}

// ---------------- W -> bf16 transposed [r][col=e][k=d] (aliases dead cnt_c) ----------------
__global__ void k_cvt_w(const float* __restrict__ W_rel, const float* __restrict__ W_self,
                        unsigned short* __restrict__ Wt) {
  int i = blockIdx.x * 256 + threadIdx.x;  // over 9*16384
  if (i >= 9 * 16384) return;
  int r = i >> 14, rem = i & 16383;
  int e = rem >> 7, d = rem & 127;
  float v = (r < 8) ? W_rel[r * 16384 + d * 128 + e] : W_self[d * 128 + e];
  Wt[i] = f2bf(v);
}

// ---------------- fused RGCN GEMM on matrix cores ----------------
// 32-mid tile, 256 threads (4 waves, 1x4 wave grid, 32x32 sub-tile/wave),
// 1024 blocks -> 4 blocks/CU (round-9 was grid-capped at 2). Branchless
// register-prefetch gather (8 idx + 32 independent X loads, 0/1-weight FMA).
__global__ __launch_bounds__(256) void k_fused(
    const float* __restrict__ X, const unsigned short* __restrict__ Wt,
    const float* __restrict__ bvec, const int* __restrict__ uniq,
    const int* __restrict__ counter, const int* __restrict__ seg_start,
    const int* __restrict__ s_src, float* __restrict__ Hacc) {
  __shared__ __align__(16) unsigned short a_lds[32 * 128];   // [row][k], 16B-unit XOR-swizzled
  __shared__ __align__(16) unsigned short w_lds[128 * 128];  // [col][k], swizzled

  int nm = *counter;
  int mid0 = blockIdx.x * 32;
  if (mid0 >= nm) return;

  int t = threadIdx.x;
  int er = t >> 3, oct = t & 7;                   // staging: row er (0..31), chunk oct
  int lane = t & 63, l15 = lane & 15, lg = lane >> 4;
  int wc = t >> 6;                                // wave col-block (0..3); wr == 0
  int mid = mid0 + er;

  f32x4 acc[2][2];
#pragma unroll
  for (int m = 0; m < 2; ++m)
#pragma unroll
    for (int n = 0; n < 2; ++n) {
      f32x4 z = {0.f, 0.f, 0.f, 0.f};
      acc[m][n] = z;
    }

  for (int r = 0; r < 9; ++r) {
    __syncthreads();  // previous compute done before overwriting LDS

    {  // stage W tile: Wt[r] (2048 uint4) -> w_lds, swizzle unit ^ ((unit>>4)&7)
      const uint4* wg = (const uint4*)(Wt + r * 16384);
#pragma unroll
      for (int i = 0; i < 8; ++i) {
        int v = t + i * 256;
        int u = v ^ ((v >> 4) & 7);
        *(uint4*)&w_lds[u * 8] = wg[v];
      }
    }

    {  // stage A row er chunk oct
      float aa[16];
#pragma unroll
      for (int q = 0; q < 16; ++q) aa[q] = 0.f;
      if (r < 8) {
        int comb = mid * 8 + r;
        int s0 = seg_start[comb], s1 = seg_start[comb + 1];
        int cnt = s1 - s0;
        // branchless prefetch of up to 8 edge indices (always in-bounds)
        int rowi[8];
        float wj[8];
#pragma unroll
        for (int j = 0; j < 8; ++j) {
          int jj = (j < cnt) ? j : 0;
          int pre = s_src[s0 + jj];
          rowi[j] = (j < cnt) ? pre : 0;    // dummy -> X row 0 (cache-hot)
          wj[j] = (j < cnt) ? 1.f : 0.f;
        }
#pragma unroll
        for (int j = 0; j < 8; ++j) {
          const float4* xr = (const float4*)(X + (size_t)rowi[j] * 128) + oct * 4;
          float w = wj[j];
#pragma unroll
          for (int q = 0; q < 4; ++q) {
            float4 v = xr[q];
            aa[q * 4 + 0] += w * v.x; aa[q * 4 + 1] += w * v.y;
            aa[q * 4 + 2] += w * v.z; aa[q * 4 + 3] += w * v.w;
          }
        }
        for (int e = s0 + 8; e < s1; ++e) {  // rare tail (P[cnt>8] ~ 1e-4)
          const float4* xr = (const float4*)(X + (size_t)s_src[e] * 128) + oct * 4;
#pragma unroll
          for (int q = 0; q < 4; ++q) {
            float4 v = xr[q];
            aa[q * 4 + 0] += v.x; aa[q * 4 + 1] += v.y;
            aa[q * 4 + 2] += v.z; aa[q * 4 + 3] += v.w;
          }
        }
        if (cnt > 1) {
          float sc = 1.0f / (float)cnt;
#pragma unroll
          for (int q = 0; q < 16; ++q) aa[q] *= sc;
        }
      } else if (mid < nm) {
        const float4* xr = (const float4*)(X + (size_t)uniq[mid] * 128) + oct * 4;
#pragma unroll
        for (int q = 0; q < 4; ++q) {
          float4 v = xr[q];
          aa[q * 4 + 0] = v.x; aa[q * 4 + 1] = v.y;
          aa[q * 4 + 2] = v.z; aa[q * 4 + 3] = v.w;
        }
      }
      unsigned int p[8];
#pragma unroll
      for (int q = 0; q < 8; ++q)
        p[q] = (unsigned int)f2bf(aa[q * 2]) | ((unsigned int)f2bf(aa[q * 2 + 1]) << 16);
      int unit0 = er * 16 + oct * 2, sw = er & 7;
      uint4 p0 = make_uint4(p[0], p[1], p[2], p[3]);
      uint4 p1 = make_uint4(p[4], p[5], p[6], p[7]);
      *(uint4*)&a_lds[((unit0) ^ sw) * 8] = p0;
      *(uint4*)&a_lds[((unit0 + 1) ^ sw) * 8] = p1;
    }
    __syncthreads();

    // ---- MFMA: 4 k-blocks x (2 row-frags x 2 col-frags)
#pragma unroll
    for (int kb = 0; kb < 4; ++kb) {
      int ku = kb * 4 + lg;  // 16B unit index along k for this lane group
      bf16x8 af[2], bfr[2];
#pragma unroll
      for (int m = 0; m < 2; ++m) {
        int row = m * 16 + l15;
        af[m] = *(const bf16x8*)&a_lds[((row * 16 + ku) ^ (row & 7)) * 8];
      }
#pragma unroll
      for (int n = 0; n < 2; ++n) {
        int col = wc * 32 + n * 16 + l15;
        bfr[n] = *(const bf16x8*)&w_lds[((col * 16 + ku) ^ (col & 7)) * 8];
      }
#pragma unroll
      for (int m = 0; m < 2; ++m)
#pragma unroll
        for (int n = 0; n < 2; ++n)
          acc[m][n] = __builtin_amdgcn_mfma_f32_16x16x32_bf16(af[m], bfr[n], acc[m][n], 0, 0, 0);
    }
  }

  // epilogue: bias + relu, plain stores. C/D map: col=lane&15, row=(lane>>4)*4+reg
#pragma unroll
  for (int m = 0; m < 2; ++m) {
#pragma unroll
    for (int n = 0; n < 2; ++n) {
      int col = wc * 32 + n * 16 + l15;
      float bv = bvec[col];
#pragma unroll
      for (int q = 0; q < 4; ++q) {
        int row = mid0 + m * 16 + lg * 4 + q;
        float v = acc[m][n][q] + bv;
        Hacc[(size_t)row * 128 + col] = v > 0.f ? v : 0.f;
      }
    }
  }
}

// ---------------- DistMult score: one wave per triple ----------------
__global__ void k_score(const float* __restrict__ H, const int* __restrict__ map,
                        const float* __restrict__ rel_emb, const int* __restrict__ tri_nodes,
                        const int* __restrict__ tri_rel, float* __restrict__ out, int B) {
  int w = (blockIdx.x * blockDim.x + threadIdx.x) >> 6;
  int lane = threadIdx.x & 63;
  if (w >= B) return;
  int s = map[tri_nodes[w * 2]];
  int o = map[tri_nodes[w * 2 + 1]];
  const float* hs = H + (size_t)s * 128;
  const float* ho = H + (size_t)o * 128;
  const float* rr = rel_emb + (size_t)tri_rel[w] * 128;
  float p = hs[lane] * ho[lane] * rr[lane] + hs[lane + 64] * ho[lane + 64] * rr[lane + 64];
#pragma unroll
  for (int ofs = 32; ofs > 0; ofs >>= 1) p += __shfl_down(p, ofs);
  if (lane == 0) out[w] = p;
}

extern "C" void kernel_launch(void* const* d_in, const int* in_sizes, int n_in,
                              void* d_out, int out_size, void* d_ws, size_t ws_size,
                              hipStream_t stream) {
  const float* X       = (const float*)d_in[0];
  const float* W_rel   = (const float*)d_in[1];
  const float* W_self  = (const float*)d_in[2];
  const float* bvec    = (const float*)d_in[3];
  const float* rel_emb = (const float*)d_in[4];
  const int* edge_src  = (const int*)d_in[5];
  const int* edge_dst  = (const int*)d_in[6];
  const int* edge_rel  = (const int*)d_in[7];
  const int* tri_nodes = (const int*)d_in[8];
  const int* tri_rel   = (const int*)d_in[9];

  int N  = in_sizes[0] / 128;   // 100000
  int E  = in_sizes[5];         // 1600000
  int nt = in_sizes[8];         // 2*B = 32768
  int B  = in_sizes[9];         // 16384
  int M  = nt * 8;              // 262144 combs

  char* ws = (char*)d_ws;
  int* map       = (int*)ws;                 // N
  int* counter   = map + N;                  // 1 (+pad 64)
  int* uniq      = counter + 64;             // nt
  int* cnt_c     = uniq + nt;                // M  (reused as Wt after scan_s3)
  int* seg_start = cnt_c + M;                // M+1 (+pad 64)
  int* seg_ofs   = seg_start + M + 64;       // M
  int* bsum      = seg_ofs + M;              // 256
  int* s_src     = bsum + 256;               // E
  float* Hacc    = (float*)(s_src + E);      // nt*128 floats
  unsigned short* Wt = (unsigned short*)cnt_c;  // 9*16384 bf16, aliases cnt_c
  // total ws use: ~26.9 MB (within the 31.5 MB high-water mark proven in rounds 2-4)

  hipMemsetAsync(map, 0xFF, (size_t)N * 4, stream);  // -1
  hipMemsetAsync(counter, 0, 64 * 4, stream);
  hipMemsetAsync(cnt_c, 0, (size_t)M * 4, stream);

  int eblocks = (E + 255) / 256;  // one thread per edge: max probe parallelism
  k_build_map<<<(nt + 255) / 256, 256, 0, stream>>>(tri_nodes, map, uniq, counter, nt);
  k_count<<<eblocks, 256, 0, stream>>>(edge_dst, edge_rel, map, cnt_c, E);
  k_scan_s1<<<256, 256, 0, stream>>>(cnt_c, bsum);
  k_scan_s2<<<1, 256, 0, stream>>>(bsum, seg_start, M);
  k_scan_s3<<<256, 256, 0, stream>>>(cnt_c, bsum, seg_start, seg_ofs);
  // cnt_c is dead from here on; overwrite it with the bf16 weights
  k_cvt_w<<<(9 * 16384 + 255) / 256, 256, 0, stream>>>(W_rel, W_self, Wt);
  k_scatter<<<eblocks, 256, 0, stream>>>(edge_src, edge_dst, edge_rel, map, seg_ofs,
                                         s_src, E);
  k_fused<<<nt / 32, 256, 0, stream>>>(X, Wt, bvec, uniq, counter, seg_start, s_src, Hacc);
  k_score<<<(B * 64 + 255) / 256, 256, 0, stream>>>(Hacc, map, rel_emb, tri_nodes,
                                                    tri_rel, (float*)d_out, B);
}

// Round 11
// 137.702 us; speedup vs baseline: 3.4436x; 1.2565x over previous
//
#include <hip/hip_runtime.h>

typedef float f32x4 __attribute__((ext_vector_type(4)));
typedef short bf16x8 __attribute__((ext_vector_type(8)));

__device__ __forceinline__ unsigned short f2bf(float f) {
  unsigned int u = __float_as_uint(f);
  u += 0x7FFFu + ((u >> 16) & 1u);  // RNE
  return (unsigned short)(u >> 16);
}

// ---------------- build node -> compact id map ----------------
__global__ void k_build_map(const int* __restrict__ tri_nodes, int* __restrict__ map,
                            int* __restrict__ uniq, int* __restrict__ counter, int n) {
  int i = blockIdx.x * blockDim.x + threadIdx.x;
  if (i >= n) return;
  int node = tri_nodes[i];
  int old = atomicCAS(&map[node], -1, -2);
  if (old == -1) {
    int mid = atomicAdd(counter, 1);
    uniq[mid] = node;
    map[node] = mid;
  }
}

// ---------------- count needed edges per comb = mid*8+rel ----------------
__global__ void k_count(const int* __restrict__ edst, const int* __restrict__ erel,
                        const int* __restrict__ map, int* __restrict__ cnt_c, int E) {
  int i = blockIdx.x * blockDim.x + threadIdx.x;
  if (i >= E) return;
  int mid = map[edst[i]];
  if (mid >= 0) atomicAdd(&cnt_c[mid * 8 + erel[i]], 1);
}

// ---------------- hierarchical exclusive scan over M=262144 entries ----------------
__global__ __launch_bounds__(256) void k_scan_s1(const int* __restrict__ cnt_c,
                                                 int* __restrict__ bsum) {
  __shared__ int sh[256];
  int tid = threadIdx.x;
  int base = blockIdx.x * 1024 + tid * 4;
  int s = cnt_c[base] + cnt_c[base + 1] + cnt_c[base + 2] + cnt_c[base + 3];
  sh[tid] = s;
  __syncthreads();
  for (int o = 1; o < 256; o <<= 1) {
    int x = (tid >= o) ? sh[tid - o] : 0;
    __syncthreads();
    sh[tid] += x;
    __syncthreads();
  }
  if (tid == 255) bsum[blockIdx.x] = sh[255];
}
__global__ __launch_bounds__(256) void k_scan_s2(int* __restrict__ bsum,
                                                 int* __restrict__ seg_start, int M) {
  __shared__ int sh[256];
  int tid = threadIdx.x;
  int v = bsum[tid];
  sh[tid] = v;
  __syncthreads();
  for (int o = 1; o < 256; o <<= 1) {
    int x = (tid >= o) ? sh[tid - o] : 0;
    __syncthreads();
    sh[tid] += x;
    __syncthreads();
  }
  bsum[tid] = sh[tid] - v;  // exclusive
  if (tid == 255) seg_start[M] = sh[255];
}
__global__ __launch_bounds__(256) void k_scan_s3(const int* __restrict__ cnt_c,
                                                 const int* __restrict__ bsum,
                                                 int* __restrict__ seg_start,
                                                 int* __restrict__ seg_ofs) {
  __shared__ int sh[256];
  int tid = threadIdx.x;
  int base = blockIdx.x * 1024 + tid * 4;
  int c0 = cnt_c[base], c1 = cnt_c[base + 1], c2 = cnt_c[base + 2], c3 = cnt_c[base + 3];
  int s = c0 + c1 + c2 + c3;
  sh[tid] = s;
  __syncthreads();
  for (int o = 1; o < 256; o <<= 1) {
    int x = (tid >= o) ? sh[tid - o] : 0;
    __syncthreads();
    sh[tid] += x;
    __syncthreads();
  }
  int run = bsum[blockIdx.x] + sh[tid] - s;
  seg_start[base] = run; seg_ofs[base] = run; run += c0;
  seg_start[base + 1] = run; seg_ofs[base + 1] = run; run += c1;
  seg_start[base + 2] = run; seg_ofs[base + 2] = run; run += c2;
  seg_start[base + 3] = run; seg_ofs[base + 3] = run;
}

// ---------------- scatter needed edge srcs into comb-sorted order ----------------
__global__ void k_scatter(const int* __restrict__ esrc, const int* __restrict__ edst,
                          const int* __restrict__ erel, const int* __restrict__ map,
                          int* __restrict__ seg_ofs, int* __restrict__ s_src, int E) {
  int i = blockIdx.x * blockDim.x + threadIdx.x;
  if (i >= E) return;
  int mid = map[edst[i]];
  if (mid >= 0) {
    int comb = mid * 8 + erel[i];
    int pos = atomicAdd(&seg_ofs[comb], 1);
    s_src[pos] = esrc[i];
  }
}

// ---------------- W -> bf16 FRAGMENT-MAJOR: Wf[((r*16+ku)*128+col)*8+j] = W[r][ku*8+j][col]
// Lane l of a wave loads (col = c0 + (l&15), ku = kb*4 + (l>>4)): consecutive
// lanes -> consecutive 16B chunks (4 x 256B coalesced segments per load).
__global__ void k_cvt_w(const float* __restrict__ W_rel, const float* __restrict__ W_self,
                        unsigned short* __restrict__ Wf) {
  int i = blockIdx.x * 256 + threadIdx.x;  // over 9*16384 bf16 elements
  if (i >= 9 * 16384) return;
  int j = i & 7;
  int tmp = i >> 3;
  int col = tmp & 127;
  int ku = (tmp >> 7) & 15;
  int r = tmp >> 11;
  int d = ku * 8 + j;
  float v = (r < 8) ? W_rel[r * 16384 + d * 128 + col] : W_self[d * 128 + col];
  Wf[i] = f2bf(v);
}

// ---------------- fused RGCN GEMM on matrix cores ----------------
// Max-occupancy config: 16-mid tile, 256 threads (4 waves, each 16 rows x 32
// cols), grid 2048 = 8 blocks/CU, LDS 4 KB, target VGPR <= 64 -> 32 waves/CU.
// B-fragments load straight from fragment-major Wf (coalesced, L2-hot); only
// the A tile goes through LDS. Serial per-segment gather (TLP hides latency).
__global__ __launch_bounds__(256) void k_fused(
    const float* __restrict__ X, const unsigned short* __restrict__ Wf,
    const float* __restrict__ bvec, const int* __restrict__ uniq,
    const int* __restrict__ counter, const int* __restrict__ seg_start,
    const int* __restrict__ s_src, float* __restrict__ Hacc) {
  __shared__ __align__(16) unsigned short a_lds[16 * 128];  // 4 KB, 16B-unit XOR-swizzled

  int nm = *counter;
  int mid0 = blockIdx.x * 16;
  if (mid0 >= nm) return;

  int t = threadIdx.x;
  int er = t >> 4, seg = t & 15;   // staging: row er (0..15), 16B-chunk seg (0..15)
  int lane = t & 63, l15 = lane & 15, lg = lane >> 4;
  int wc = t >> 6;                 // wave col-block (0..3)
  int mid = mid0 + er;

  f32x4 acc[2];
  {
    f32x4 z = {0.f, 0.f, 0.f, 0.f};
    acc[0] = z; acc[1] = z;
  }

  for (int r = 0; r < 9; ++r) {
    __syncthreads();  // previous MFMA done before overwriting a_lds

    {  // stage A row er chunk seg (8 floats -> 8 bf16 = one 16B unit)
      float aa[8];
#pragma unroll
      for (int q = 0; q < 8; ++q) aa[q] = 0.f;
      if (r < 8) {
        int comb = mid * 8 + r;
        int s0 = seg_start[comb], s1 = seg_start[comb + 1];
        for (int e = s0; e < s1; ++e) {
          const float4* xr = (const float4*)(X + (size_t)s_src[e] * 128) + seg * 2;
          float4 v0 = xr[0], v1 = xr[1];
          aa[0] += v0.x; aa[1] += v0.y; aa[2] += v0.z; aa[3] += v0.w;
          aa[4] += v1.x; aa[5] += v1.y; aa[6] += v1.z; aa[7] += v1.w;
        }
        int cnt = s1 - s0;
        if (cnt > 1) {
          float sc = 1.0f / (float)cnt;
#pragma unroll
          for (int q = 0; q < 8; ++q) aa[q] *= sc;
        }
      } else if (mid < nm) {
        const float4* xr = (const float4*)(X + (size_t)uniq[mid] * 128) + seg * 2;
        float4 v0 = xr[0], v1 = xr[1];
        aa[0] = v0.x; aa[1] = v0.y; aa[2] = v0.z; aa[3] = v0.w;
        aa[4] = v1.x; aa[5] = v1.y; aa[6] = v1.z; aa[7] = v1.w;
      }
      uint4 p;
      p.x = (unsigned int)f2bf(aa[0]) | ((unsigned int)f2bf(aa[1]) << 16);
      p.y = (unsigned int)f2bf(aa[2]) | ((unsigned int)f2bf(aa[3]) << 16);
      p.z = (unsigned int)f2bf(aa[4]) | ((unsigned int)f2bf(aa[5]) << 16);
      p.w = (unsigned int)f2bf(aa[6]) | ((unsigned int)f2bf(aa[7]) << 16);
      *(uint4*)&a_lds[(((er * 16 + seg) ^ (er & 7)) * 8)] = p;
    }
    __syncthreads();  // a_lds ready

    // ---- MFMA: 4 k-blocks x 2 col-frags; B direct from coalesced Wf
    const unsigned short* wf = Wf + r * 16384;
#pragma unroll
    for (int kb = 0; kb < 4; ++kb) {
      int ku = kb * 4 + lg;
      bf16x8 af = *(const bf16x8*)&a_lds[((l15 * 16 + ku) ^ (l15 & 7)) * 8];
#pragma unroll
      for (int n = 0; n < 2; ++n) {
        int col = wc * 32 + n * 16 + l15;
        bf16x8 bfr = *(const bf16x8*)(wf + ((size_t)(ku * 128 + col)) * 8);
        acc[n] = __builtin_amdgcn_mfma_f32_16x16x32_bf16(af, bfr, acc[n], 0, 0, 0);
      }
    }
  }

  // epilogue: bias + relu, plain stores. C/D map: col=lane&15, row=(lane>>4)*4+reg
#pragma unroll
  for (int n = 0; n < 2; ++n) {
    int col = wc * 32 + n * 16 + l15;
    float bv = bvec[col];
#pragma unroll
    for (int q = 0; q < 4; ++q) {
      int row = mid0 + lg * 4 + q;
      float v = acc[n][q] + bv;
      Hacc[(size_t)row * 128 + col] = v > 0.f ? v : 0.f;
    }
  }
}

// ---------------- DistMult score: one wave per triple ----------------
__global__ void k_score(const float* __restrict__ H, const int* __restrict__ map,
                        const float* __restrict__ rel_emb, const int* __restrict__ tri_nodes,
                        const int* __restrict__ tri_rel, float* __restrict__ out, int B) {
  int w = (blockIdx.x * blockDim.x + threadIdx.x) >> 6;
  int lane = threadIdx.x & 63;
  if (w >= B) return;
  int s = map[tri_nodes[w * 2]];
  int o = map[tri_nodes[w * 2 + 1]];
  const float* hs = H + (size_t)s * 128;
  const float* ho = H + (size_t)o * 128;
  const float* rr = rel_emb + (size_t)tri_rel[w] * 128;
  float p = hs[lane] * ho[lane] * rr[lane] + hs[lane + 64] * ho[lane + 64] * rr[lane + 64];
#pragma unroll
  for (int ofs = 32; ofs > 0; ofs >>= 1) p += __shfl_down(p, ofs);
  if (lane == 0) out[w] = p;
}

extern "C" void kernel_launch(void* const* d_in, const int* in_sizes, int n_in,
                              void* d_out, int out_size, void* d_ws, size_t ws_size,
                              hipStream_t stream) {
  const float* X       = (const float*)d_in[0];
  const float* W_rel   = (const float*)d_in[1];
  const float* W_self  = (const float*)d_in[2];
  const float* bvec    = (const float*)d_in[3];
  const float* rel_emb = (const float*)d_in[4];
  const int* edge_src  = (const int*)d_in[5];
  const int* edge_dst  = (const int*)d_in[6];
  const int* edge_rel  = (const int*)d_in[7];
  const int* tri_nodes = (const int*)d_in[8];
  const int* tri_rel   = (const int*)d_in[9];

  int N  = in_sizes[0] / 128;   // 100000
  int E  = in_sizes[5];         // 1600000
  int nt = in_sizes[8];         // 2*B = 32768
  int B  = in_sizes[9];         // 16384
  int M  = nt * 8;              // 262144 combs

  char* ws = (char*)d_ws;
  int* map       = (int*)ws;                 // N
  int* counter   = map + N;                  // 1 (+pad 64)
  int* uniq      = counter + 64;             // nt
  int* cnt_c     = uniq + nt;                // M  (reused as Wf after scan_s3)
  int* seg_start = cnt_c + M;                // M+1 (+pad 64)
  int* seg_ofs   = seg_start + M + 64;       // M
  int* bsum      = seg_ofs + M;              // 256
  int* s_src     = bsum + 256;               // E
  float* Hacc    = (float*)(s_src + E);      // nt*128 floats
  unsigned short* Wf = (unsigned short*)cnt_c;  // 9*16384 bf16, aliases dead cnt_c
  // total ws use: ~26.9 MB (within the 31.5 MB high-water mark proven in rounds 2-4)

  hipMemsetAsync(map, 0xFF, (size_t)N * 4, stream);  // -1
  hipMemsetAsync(counter, 0, 64 * 4, stream);
  hipMemsetAsync(cnt_c, 0, (size_t)M * 4, stream);

  int eblocks = (E + 255) / 256;  // one thread per edge: max probe parallelism
  k_build_map<<<(nt + 255) / 256, 256, 0, stream>>>(tri_nodes, map, uniq, counter, nt);
  k_count<<<eblocks, 256, 0, stream>>>(edge_dst, edge_rel, map, cnt_c, E);
  k_scan_s1<<<256, 256, 0, stream>>>(cnt_c, bsum);
  k_scan_s2<<<1, 256, 0, stream>>>(bsum, seg_start, M);
  k_scan_s3<<<256, 256, 0, stream>>>(cnt_c, bsum, seg_start, seg_ofs);
  // cnt_c is dead from here on; overwrite it with the bf16 fragment-major weights
  k_cvt_w<<<(9 * 16384 + 255) / 256, 256, 0, stream>>>(W_rel, W_self, Wf);
  k_scatter<<<eblocks, 256, 0, stream>>>(edge_src, edge_dst, edge_rel, map, seg_ofs,
                                         s_src, E);
  k_fused<<<nt / 16, 256, 0, stream>>>(X, Wf, bvec, uniq, counter, seg_start, s_src, Hacc);
  k_score<<<(B * 64 + 255) / 256, 256, 0, stream>>>(Hacc, map, rel_emb, tri_nodes,
                                                    tri_rel, (float*)d_out, B);
}